// Round 4
// baseline (26831.653 us; speedup 1.0000x reference)
//
#include <hip/hip_runtime.h>
#include <hip/hip_bf16.h>

// GRU backbone: B=64 S=2048 D=256 V=256 L=4
// NEW this round: persistent pipelined kernel. 256 blocks x 512 thr:
//   blocks 0..63  : scan role, (layer l = blk>>4, batch-tile bi = blk&15), round-3 inner loop
//   blocks 64..255: gi GEMM workers (192 = 32 batch-pair-tiles x 6 N-tiles per layer-chunk)
// Layers overlap with ~2-chunk lag (chunk = 64 steps). gi flows through 2-slot/layer ring
// buffers (6 MB/slot). Flags: scanprog[4][16] (chunks done), jobdone[4][32] (worker counts),
// agent-scope atomics + __threadfence for cross-XCD release/acquire.
// Buffer overlay (chunk-aligned, structurally ordered by flag chain):
//   bufA: embed seq_e -> seq1 (scan1) -> seq3 (scan3, read by final GEMM)
//   bufB: seq0 (scan0) -> seq2 (scan2)
// Deadlock-free: wait graph references strictly earlier (entity, chunk) coords; co-residency
// forced (256 blocks x 8 waves x <=256 regs = exactly 1 block/CU). Spins bounded (fail clean).

#define B_ 64
#define S_ 2048
#define D_ 256
#define V_ 256
#define L_ 4
#define CHUNK_ 64
#define NCHUNK_ 32
#define LAG_ 2
#define NWORK_ 192
#define SLOTDW_ (16 * 64 * 1536)   // dwords per ring slot (1,572,864)

typedef short  s16x8 __attribute__((ext_vector_type(8)));
typedef float  f32x4 __attribute__((ext_vector_type(4)));

static __device__ __forceinline__ unsigned short f2b(float f){
  union { float f; unsigned int u; } v; v.f = f;
  unsigned int u = v.u;
  return (unsigned short)((u + 0x7FFFu + ((u >> 16) & 1u)) >> 16);  // RNE
}
static __device__ __forceinline__ float b2f_lo(unsigned int u){
  union { unsigned int u; float f; } v; v.u = u << 16; return v.f;
}
static __device__ __forceinline__ float b2f_hi(unsigned int u){
  union { unsigned int u; float f; } v; v.u = u & 0xffff0000u; return v.f;
}

static __device__ __forceinline__ void lds_load16(void* lds, const void* g){
  __builtin_amdgcn_global_load_lds(
      (const __attribute__((address_space(1))) unsigned int*)g,
      (__attribute__((address_space(3))) unsigned int*)lds, 16, 0, 0);
}

static __device__ __forceinline__ int aload(const int* p){
  return __hip_atomic_load(p, __ATOMIC_RELAXED, __HIP_MEMORY_SCOPE_AGENT);
}
static __device__ __forceinline__ void spin_ge(const int* p, int tgt){
  int n = 0;
  while (aload(p) < tgt && n < 4000000){ __builtin_amdgcn_s_sleep(32); ++n; }
}
static __device__ __forceinline__ void spin_min16_ge(const int* p, int tgt){
  int n = 0;
  for (;;){
    int m = 0x7fffffff;
    #pragma unroll
    for (int i = 0; i < 16; ++i) m = min(m, aload(p + i));
    if (m >= tgt || n > 4000000) break;
    __builtin_amdgcn_s_sleep(32); ++n;
  }
}

__global__ void cast_bf16_kernel(const float* __restrict__ src,
                                 unsigned short* __restrict__ dst, int n){
  int i = blockIdx.x * 256 + threadIdx.x;
  if (i < n) dst[i] = f2b(src[i]);
}

__global__ void embed_kernel(const int* __restrict__ x, const float* __restrict__ emb,
                             unsigned short* __restrict__ seq){
  int bs = blockIdx.x;
  int d  = threadIdx.x;
  int tok = x[bs];
  seq[(size_t)bs * D_ + d] = f2b(emb[tok * D_ + d]);
}

__global__ void init_flags_kernel(int* flags){
  int i = threadIdx.x;
  if (i < 192) flags[i] = 0;
}

// Persistent pipelined kernel. See header comment for protocol.
__global__ __launch_bounds__(512, 2) void gru_pipe(
    unsigned short* bufA, unsigned short* bufB,
    unsigned int* ring,
    const unsigned short* wih, const unsigned short* whh,
    const float* bih, const float* bhh,
    int* flags)
{
  __shared__ __align__(16) unsigned short smem[8192];   // 16 KB (scan: h dbuf | worker: As+Bs)
  const int blk = blockIdx.x;
  const int tid = threadIdx.x, lane = tid & 63, w = tid >> 6;
  const int col = lane & 15, q = lane >> 4;
  int* scanprog = flags;        // [4][16] chunks completed per scan block
  int* jobdone  = flags + 64;   // [4][32] worker tiles completed per (layer, chunk)

  if (blk < 64){
    // ---------------- scan role (round-3 inner loop + chunk gates) ----------------
    const int l = blk >> 4, bi = blk & 15;
    const unsigned short* Wh = whh + (size_t)l * 768 * 256;
    const float* bh = bhh + l * 768;
    unsigned short* outp = (l & 1) ? bufA : bufB;
    const unsigned int* ringL = ring + (size_t)l * 2 * SLOTDW_;
    const int dbase = w * 32;   // wave owns d in [dbase, dbase+32)

    // Wh fragments in registers: bw[g*2+t2][kk], B-layout (n=lane&15, k=q*8+j)
    s16x8 bw[6][8];
    float bhv[6];
    #pragma unroll
    for (int g = 0; g < 3; ++g)
      #pragma unroll
      for (int t2 = 0; t2 < 2; ++t2){
        int gcol = g * 256 + dbase + t2 * 16 + col;
        bhv[g * 2 + t2] = bh[gcol];
        #pragma unroll
        for (int kk = 0; kk < 8; ++kk)
          bw[g * 2 + t2][kk] = *(const s16x8*)(Wh + gcol * 256 + kk * 32 + q * 8);
      }

    unsigned short* hb0 = smem;          // h dbuf in A-frag order
    unsigned short* hb1 = smem + 4096;
    for (int i = tid; i < 8192; i += 512) smem[i] = 0;   // rows 4q+1..3 stay 0 forever

    float hprev[2] = {0.f, 0.f};
    const size_t obase = (size_t)(bi * 4 + q) * (S_ * D_) + dbase + col;
    __syncthreads();

    auto step = [&](const unsigned short* hcur, unsigned short* hnxt,
                    unsigned int c0, unsigned int c1, unsigned int c2, int sidx){
      f32x4 acc[6];
      #pragma unroll
      for (int t = 0; t < 6; ++t){ f32x4 vv = {bhv[t], bhv[t], bhv[t], bhv[t]}; acc[t] = vv; }
      s16x8 a0 = *(const s16x8*)&hcur[lane * 8];
      #pragma unroll
      for (int kk = 0; kk < 8; ++kk){
        s16x8 aN = a0;
        if (kk < 7) aN = *(const s16x8*)&hcur[(kk + 1) * 512 + lane * 8];
        #pragma unroll
        for (int t = 0; t < 6; ++t)
          acc[t] = __builtin_amdgcn_mfma_f32_16x16x32_bf16(a0, bw[t][kk], acc[t], 0, 0, 0);
        a0 = aN;
      }
      float giR[2] = { b2f_lo(c0), b2f_hi(c1) };
      float giZ[2] = { b2f_hi(c0), b2f_lo(c2) };
      float giN[2] = { b2f_lo(c1), b2f_hi(c2) };
      #pragma unroll
      for (int t2 = 0; t2 < 2; ++t2){
        const int d = dbase + t2 * 16 + col;
        float pr = acc[t2][0]     + giR[t2];
        float pz = acc[2 + t2][0] + giZ[t2];
        float rg = __builtin_amdgcn_rcpf(1.f + __expf(-pr));
        float zg = __builtin_amdgcn_rcpf(1.f + __expf(-pz));
        float na = giN[t2] + rg * acc[4 + t2][0];
        float e2 = __expf(2.f * na);
        float ng = 1.f - 2.f * __builtin_amdgcn_rcpf(e2 + 1.f);   // tanh
        float hn = ng + zg * (hprev[t2] - ng);                    // (1-z)*n + z*h
        hprev[t2] = hn;
        unsigned short hbits = f2b(hn);
        outp[obase + (size_t)sidx * D_ + t2 * 16] = hbits;
        hnxt[(d >> 5) * 512 + ((4 * q) + 16 * ((d >> 3) & 3)) * 8 + (d & 7)] = hbits;
      }
      asm volatile("s_waitcnt lgkmcnt(0)" ::: "memory");
      __builtin_amdgcn_s_barrier();
      asm volatile("" ::: "memory");
    };

    for (int c = 0; c < NCHUNK_; ++c){
      if (tid == 0) spin_ge(&jobdone[l * 32 + c], NWORK_);   // gi chunk ready
      __syncthreads();
      __threadfence();                                       // acquire (inv stale ring lines)
      const unsigned int* gp = ringL + (size_t)(c & 1) * SLOTDW_ + bi * (64 * 1536) + (w * 64 + lane);
      unsigned int cA0 = gp[0], cA1 = gp[512], cA2 = gp[1024];
      const int sg0 = c * 64;
      for (int s2 = 0; s2 < 64; s2 += 2){
        const unsigned int* gq = gp + (size_t)(s2 + 1) * 1536;
        unsigned int cB0 = gq[0], cB1 = gq[512], cB2 = gq[1024];
        step(hb0, hb1, cA0, cA1, cA2, sg0 + s2);
        const unsigned int* gr = gp + (size_t)((s2 + 2 < 64) ? s2 + 2 : s2) * 1536;
        cA0 = gr[0]; cA1 = gr[512]; cA2 = gr[1024];
        step(hb1, hb0, cB0, cB1, cB2, sg0 + s2 + 1);
      }
      __syncthreads();                                       // drains each wave's vmcnt
      __threadfence();                                       // release seq chunk (wb L2)
      if (tid == 0)
        __hip_atomic_store(&scanprog[l * 16 + bi], c + 1, __ATOMIC_RELAXED, __HIP_MEMORY_SCOPE_AGENT);
    }
  } else {
    // ---------------- worker role: gi chunk-tile GEMMs ----------------
    const int W = blk - 64, jm = W / 6, jn = W % 6;   // batch-pair tile, N-tile
    unsigned short* As = smem;
    unsigned short* Bs = smem + 4096;
    const int mW = (w & 1) * 64, nW = (w >> 1) * 32;
    const int rr = tid >> 2, c16 = tid & 3;

    for (int T = 0; T <= NCHUNK_ - 1 + 3 * LAG_; ++T){
      for (int l = 0; l < 4; ++l){
        const int c = T - l * LAG_;
        if (c < 0 || c >= NCHUNK_) continue;
        if (tid == 0){
          spin_min16_ge(&scanprog[l * 16], c - 1);                 // ring slot free
          if (l > 0) spin_min16_ge(&scanprog[(l - 1) * 16], c + 1); // input seq chunk ready
        }
        __syncthreads();
        __threadfence();                                           // acquire (inv stale seq lines)

        const unsigned short* inA = (l & 1) ? bufB : bufA;
        const unsigned short* Bw  = wih + (size_t)l * 768 * 256;
        const float* bias = bih + l * 768;
        const unsigned short* Arow = inA
            + ((size_t)(2 * jm + (rr >> 6)) * S_ + (size_t)c * 64 + (rr & 63)) * 256;
        const unsigned short* Brow = Bw + (size_t)(jn * 128 + rr) * 256;

        f32x4 acc[4][2] = {};
        for (int k0 = 0; k0 < 256; k0 += 32){
          __syncthreads();
          lds_load16((char*)As + tid * 16, (const char*)Arow + k0 * 2 + c16 * 16);
          lds_load16((char*)Bs + tid * 16, (const char*)Brow + k0 * 2 + c16 * 16);
          __syncthreads();
          s16x8 aF[4], bF[2];
          #pragma unroll
          for (int t = 0; t < 4; ++t) aF[t] = *(const s16x8*)&As[(mW + t * 16 + col) * 32 + q * 8];
          #pragma unroll
          for (int t = 0; t < 2; ++t) bF[t] = *(const s16x8*)&Bs[(nW + t * 16 + col) * 32 + q * 8];
          #pragma unroll
          for (int mi = 0; mi < 4; ++mi)
            #pragma unroll
            for (int ni = 0; ni < 2; ++ni)
              acc[mi][ni] = __builtin_amdgcn_mfma_f32_16x16x32_bf16(aF[mi], bF[ni], acc[mi][ni], 0, 0, 0);
        }
        float bn[2];
        #pragma unroll
        for (int ni = 0; ni < 2; ++ni) bn[ni] = bias[jn * 128 + nW + ni * 16 + col];

        const int b = 2 * jm + (mW >> 6), bi2 = b >> 2, qs = b & 3;
        unsigned short* slotB = (unsigned short*)(ring + (size_t)(l * 2 + (c & 1)) * SLOTDW_);
        #pragma unroll
        for (int mi = 0; mi < 4; ++mi)
          #pragma unroll
          for (int ni = 0; ni < 2; ++ni)
            #pragma unroll
            for (int i = 0; i < 4; ++i){
              int sL = mi * 16 + 4 * q + i;                 // step within chunk
              int cN = jn * 128 + nW + ni * 16 + col;       // gate column 0..767
              int g = cN >> 8, d = cN & 255;
              int lane_s = (d >> 5) * 64 + qs * 16 + (d & 15);
              int j = ((d >> 4) & 1) * 3 + g;
              slotB[(((size_t)(bi2 * 64 + sL) * 3 + (j >> 1)) * 512 + lane_s) * 2 + (j & 1)]
                  = f2b(acc[mi][ni][i] + bn[ni]);
            }
        __syncthreads();                                   // drain stores
        __threadfence();                                   // release ring tile
        if (tid == 0)
          __hip_atomic_fetch_add(&jobdone[l * 32 + c], 1, __ATOMIC_RELAXED, __HIP_MEMORY_SCOPE_AGENT);
      }
    }
  }
}

// Final logits GEMM: C[M,N] = A[M,K] * Bw[N,K]^T + bias, f32 out. 128x128 tile, BK=32.
__global__ __launch_bounds__(256) void gemm_out(const unsigned short* __restrict__ A,
                                                const unsigned short* __restrict__ Bw,
                                                const float* __restrict__ bias,
                                                float* __restrict__ C,
                                                int M, int N, int K, int ldc){
  __shared__ __align__(16) unsigned short As[128 * 32];
  __shared__ __align__(16) unsigned short Bs[128 * 32];
  const int tid = threadIdx.x, lane = tid & 63, w = tid >> 6;
  const int col = lane & 15, q = lane >> 4;
  const int m0 = blockIdx.x * 128, n0 = blockIdx.y * 128;
  const int mW = (w & 1) * 64, nW = (w >> 1) * 64;
  const size_t rowb = (size_t)K * 2;

  f32x4 acc[4][4] = {};
  for (int k0 = 0; k0 < K; k0 += 32){
    __syncthreads();
    #pragma unroll
    for (int inst = 0; inst < 2; ++inst){
      int c = inst * 256 + w * 64 + lane;
      int row = c >> 2, c16 = c & 3;
      lds_load16((char*)As + (inst * 4096 + w * 1024),
                 (const char*)A  + (size_t)(m0 + row) * rowb + (size_t)k0 * 2 + c16 * 16);
      lds_load16((char*)Bs + (inst * 4096 + w * 1024),
                 (const char*)Bw + (size_t)(n0 + row) * rowb + (size_t)k0 * 2 + c16 * 16);
    }
    __syncthreads();
    s16x8 aF[4], bF[4];
    #pragma unroll
    for (int t = 0; t < 4; ++t){
      aF[t] = *(const s16x8*)&As[(mW + t * 16 + col) * 32 + q * 8];
      bF[t] = *(const s16x8*)&Bs[(nW + t * 16 + col) * 32 + q * 8];
    }
    #pragma unroll
    for (int mi = 0; mi < 4; ++mi)
      #pragma unroll
      for (int ni = 0; ni < 4; ++ni)
        acc[mi][ni] = __builtin_amdgcn_mfma_f32_16x16x32_bf16(aF[mi], bF[ni], acc[mi][ni], 0, 0, 0);
  }
  float bn[4];
  #pragma unroll
  for (int ni = 0; ni < 4; ++ni) bn[ni] = bias[n0 + nW + ni * 16 + col];
  #pragma unroll
  for (int mi = 0; mi < 4; ++mi)
    #pragma unroll
    for (int ni = 0; ni < 4; ++ni)
      #pragma unroll
      for (int i = 0; i < 4; ++i){
        int r  = m0 + mW + mi * 16 + 4 * q + i;
        int cN = n0 + nW + ni * 16 + col;
        C[(size_t)r * ldc + cN] = acc[mi][ni][i] + bn[ni];
      }
}

extern "C" void kernel_launch(void* const* d_in, const int* in_sizes, int n_in,
                              void* d_out, int out_size, void* d_ws, size_t ws_size,
                              hipStream_t stream){
  const int*   x    = (const int*)  d_in[0];
  const float* emb  = (const float*)d_in[1];
  const float* Wih  = (const float*)d_in[2];
  const float* Whh  = (const float*)d_in[3];
  const float* bih  = (const float*)d_in[4];
  const float* bhh  = (const float*)d_in[5];
  const float* Wout = (const float*)d_in[6];
  const float* bout = (const float*)d_in[7];
  float* out = (float*)d_out;

  char* ws = (char*)d_ws;
  unsigned short* bufA  = (unsigned short*)(ws);                 // 67,108,864 B (seq_e/seq1/seq3)
  unsigned short* bufB  = (unsigned short*)(ws +  67108864);     // 67,108,864 B (seq0/seq2)
  unsigned int*   ring  = (unsigned int*)  (ws + 134217728);     // 50,331,648 B (4 layers x 2 slots)
  unsigned short* wihB  = (unsigned short*)(ws + 184549376);     //  1,572,864 B
  unsigned short* whhB  = (unsigned short*)(ws + 186122240);     //  1,572,864 B
  unsigned short* woutB = (unsigned short*)(ws + 187695104);     //    131,072 B
  int*            flags = (int*)           (ws + 187826176);     //        768 B

  cast_bf16_kernel<<<3072, 256, 0, stream>>>(Wih,  wihB,  L_ * 768 * 256);
  cast_bf16_kernel<<<3072, 256, 0, stream>>>(Whh,  whhB,  L_ * 768 * 256);
  cast_bf16_kernel<<< 256, 256, 0, stream>>>(Wout, woutB, V_ * D_);
  embed_kernel<<<B_ * S_, 256, 0, stream>>>(x, emb, bufA);
  init_flags_kernel<<<1, 256, 0, stream>>>(flags);

  gru_pipe<<<256, 512, 0, stream>>>(bufA, bufB, ring, wihB, whhB, bih, bhh, flags);

  gemm_out<<<dim3(B_ * S_ / 128, 2), 256, 0, stream>>>(bufA, woutB, bout, out,
                                                       B_ * S_, 256, 256, 256);
}

// Round 5
// 19693.854 us; speedup vs baseline: 1.3624x; 1.3624x over previous
//
#include <hip/hip_runtime.h>
#include <hip/hip_bf16.h>

// GRU backbone: B=64 S=2048 D=256 V=256 L=4
// NEW this round: self-sufficient pipelined blocks. 64 blocks x 512 thr; block = (layer
// l=blk>>4, batch-tile bi=blk&15). Each block serially alternates {scan chunk c; publish;
// own gi-GEMM chunk c+1} for its 4 batches; gi lives in a block-PRIVATE 2-slot buffer
// (same-CU visibility, no fences). Only cross-block dependency: point-to-point
// scanprog[l-1][bi] >= c+1 (round-4's proven release/acquire pattern, no 192-wide barriers,
// no ring). Layers overlap with ~1-chunk skew. Scan inner loop = round-3 verbatim.
// Buffer overlay (chunk-aligned, ordered by the flag chain):
//   bufA: embed seq_e -> seq1 -> seq3 (read by final GEMM); bufB: seq0 -> seq2.

#define B_ 64
#define S_ 2048
#define D_ 256
#define V_ 256
#define L_ 4
#define NCHUNK_ 32
#define SLOTDW_ 98304   // dwords per private gi slot: 64 steps * 1536

typedef short  s16x8 __attribute__((ext_vector_type(8)));
typedef float  f32x4 __attribute__((ext_vector_type(4)));

static __device__ __forceinline__ unsigned short f2b(float f){
  union { float f; unsigned int u; } v; v.f = f;
  unsigned int u = v.u;
  return (unsigned short)((u + 0x7FFFu + ((u >> 16) & 1u)) >> 16);  // RNE
}
static __device__ __forceinline__ float b2f_lo(unsigned int u){
  union { unsigned int u; float f; } v; v.u = u << 16; return v.f;
}
static __device__ __forceinline__ float b2f_hi(unsigned int u){
  union { unsigned int u; float f; } v; v.u = u & 0xffff0000u; return v.f;
}

static __device__ __forceinline__ void lds_load16(void* lds, const void* g){
  __builtin_amdgcn_global_load_lds(
      (const __attribute__((address_space(1))) unsigned int*)g,
      (__attribute__((address_space(3))) unsigned int*)lds, 16, 0, 0);
}

static __device__ __forceinline__ int aload(const int* p){
  return __hip_atomic_load(p, __ATOMIC_RELAXED, __HIP_MEMORY_SCOPE_AGENT);
}
static __device__ __forceinline__ void spin_ge(const int* p, int tgt){
  int n = 0;
  while (aload(p) < tgt && n < 1000000){ __builtin_amdgcn_s_sleep(32); ++n; }
}

__global__ void cast_bf16_kernel(const float* __restrict__ src,
                                 unsigned short* __restrict__ dst, int n){
  int i = blockIdx.x * 256 + threadIdx.x;
  if (i < n) dst[i] = f2b(src[i]);
}

__global__ void embed_kernel(const int* __restrict__ x, const float* __restrict__ emb,
                             unsigned short* __restrict__ seq){
  int bs = blockIdx.x;
  int d  = threadIdx.x;
  int tok = x[bs];
  seq[(size_t)bs * D_ + d] = f2b(emb[tok * D_ + d]);
}

__global__ void init_flags_kernel(int* flags){
  int i = threadIdx.x;
  if (i < 64) flags[i] = 0;
}

// Persistent pipelined kernel: 64 blocks, each owns (layer, batch-tile). See header.
__global__ __launch_bounds__(512, 2) void gru_pipe(
    unsigned short* bufA, unsigned short* bufB,
    unsigned int* gi_all,
    const unsigned short* wih, const unsigned short* whh,
    const float* bih, const float* bhh,
    int* scanprog)
{
  __shared__ __align__(16) unsigned short smem[16384];  // 32 KB: [0,8192) h dbuf | As | Bs
  const int blk = blockIdx.x;
  const int l = blk >> 4, bi = blk & 15;
  const int tid = threadIdx.x, lane = tid & 63, w = tid >> 6;
  const int col = lane & 15, q = lane >> 4;
  const int dbase = w * 32;   // scan: wave owns d in [dbase, dbase+32)

  const unsigned short* Wh = whh + (size_t)l * 768 * 256;
  const unsigned short* Wi = wih + (size_t)l * 768 * 256;
  const float* bh  = bhh + l * 768;
  const float* bip = bih + l * 768;
  const unsigned short* inp = (l & 1) ? bufB : bufA;
  unsigned short* outp      = (l & 1) ? bufA : bufB;
  unsigned int* slot0 = gi_all + (size_t)blk * (2 * SLOTDW_);

  for (int i = tid; i < 8192; i += 512) smem[i] = 0;   // h dbuf; rows 4q+1..3 stay 0 forever
  float hprev[2] = {0.f, 0.f};
  const size_t obase = (size_t)(bi * 4 + q) * (S_ * D_) + dbase + col;
  __syncthreads();

  // ---- own gi GEMM for chunk cc -> private slot cc&1 (worker-style 128x128 tiles) ----
  auto gemm_chunk = [&](int cc){
    if (l > 0){
      if (tid == 0) spin_ge(&scanprog[(l - 1) * 16 + bi], cc + 1);  // upstream seq chunk ready
      __syncthreads();
      __threadfence();                                              // acquire
    }
    unsigned short* As = smem + 8192;
    unsigned short* Bs = smem + 12288;
    const int rr = tid >> 2, c16 = tid & 3;
    const int mW = (w & 1) * 64, nW = (w >> 1) * 32;
    unsigned short* slot = (unsigned short*)(slot0 + (size_t)(cc & 1) * SLOTDW_);
    #pragma unroll 1
    for (int mt = 0; mt < 2; ++mt){
      const unsigned short* Arow = inp
          + ((size_t)(bi * 4 + 2 * mt + (rr >> 6)) * S_ + (size_t)cc * 64 + (rr & 63)) * 256;
      const int bq = 2 * mt + (mW >> 6);   // batch-in-block this wave's m-half computes
      #pragma unroll 1
      for (int jn = 0; jn < 6; ++jn){
        const unsigned short* Brow = Wi + (size_t)(jn * 128 + rr) * 256;
        f32x4 acc[4][2] = {};
        for (int k0 = 0; k0 < 256; k0 += 32){
          __syncthreads();
          lds_load16((char*)As + tid * 16, (const char*)Arow + k0 * 2 + c16 * 16);
          lds_load16((char*)Bs + tid * 16, (const char*)Brow + k0 * 2 + c16 * 16);
          __syncthreads();
          s16x8 aF[4], bF[2];
          #pragma unroll
          for (int t = 0; t < 4; ++t) aF[t] = *(const s16x8*)&As[(mW + t * 16 + col) * 32 + q * 8];
          #pragma unroll
          for (int t = 0; t < 2; ++t) bF[t] = *(const s16x8*)&Bs[(nW + t * 16 + col) * 32 + q * 8];
          #pragma unroll
          for (int mi = 0; mi < 4; ++mi)
            #pragma unroll
            for (int ni = 0; ni < 2; ++ni)
              acc[mi][ni] = __builtin_amdgcn_mfma_f32_16x16x32_bf16(aF[mi], bF[ni], acc[mi][ni], 0, 0, 0);
        }
        float bn[2];
        #pragma unroll
        for (int ni = 0; ni < 2; ++ni) bn[ni] = bip[jn * 128 + nW + ni * 16 + col];
        #pragma unroll
        for (int mi = 0; mi < 4; ++mi)
          #pragma unroll
          for (int ni = 0; ni < 2; ++ni)
            #pragma unroll
            for (int i = 0; i < 4; ++i){
              int sL = mi * 16 + 4 * q + i;               // step within chunk
              int cN = jn * 128 + nW + ni * 16 + col;     // gate column 0..767
              int g = cN >> 8, d = cN & 255;
              int lane_s = (d >> 5) * 64 + bq * 16 + (d & 15);
              int j = ((d >> 4) & 1) * 3 + g;
              slot[((size_t)(sL * 3 + (j >> 1)) * 512 + lane_s) * 2 + (j & 1)]
                  = f2b(acc[mi][ni][i] + bn[ni]);
            }
      }
    }
    __syncthreads();   // drain gi stores (same-CU L1 visibility for the scan phase)
  };

  // ---- scan chunk cc (round-3 inner loop; Wh frags reloaded per chunk) ----
  auto scan_chunk = [&](int cc){
    s16x8 bw[6][8];
    float bhv[6];
    #pragma unroll
    for (int g = 0; g < 3; ++g)
      #pragma unroll
      for (int t2 = 0; t2 < 2; ++t2){
        int gcol = g * 256 + dbase + t2 * 16 + col;
        bhv[g * 2 + t2] = bh[gcol];
        #pragma unroll
        for (int kk = 0; kk < 8; ++kk)
          bw[g * 2 + t2][kk] = *(const s16x8*)(Wh + gcol * 256 + kk * 32 + q * 8);
      }
    unsigned short* hb0 = smem;
    unsigned short* hb1 = smem + 4096;

    auto step = [&](const unsigned short* hcur, unsigned short* hnxt,
                    unsigned int c0, unsigned int c1, unsigned int c2, int sidx){
      f32x4 acc[6];
      #pragma unroll
      for (int t = 0; t < 6; ++t){ f32x4 vv = {bhv[t], bhv[t], bhv[t], bhv[t]}; acc[t] = vv; }
      s16x8 a0 = *(const s16x8*)&hcur[lane * 8];
      #pragma unroll
      for (int kk = 0; kk < 8; ++kk){
        s16x8 aN = a0;
        if (kk < 7) aN = *(const s16x8*)&hcur[(kk + 1) * 512 + lane * 8];
        #pragma unroll
        for (int t = 0; t < 6; ++t)
          acc[t] = __builtin_amdgcn_mfma_f32_16x16x32_bf16(a0, bw[t][kk], acc[t], 0, 0, 0);
        a0 = aN;
      }
      float giR[2] = { b2f_lo(c0), b2f_hi(c1) };
      float giZ[2] = { b2f_hi(c0), b2f_lo(c2) };
      float giN[2] = { b2f_lo(c1), b2f_hi(c2) };
      #pragma unroll
      for (int t2 = 0; t2 < 2; ++t2){
        const int d = dbase + t2 * 16 + col;
        float pr = acc[t2][0]     + giR[t2];
        float pz = acc[2 + t2][0] + giZ[t2];
        float rg = __builtin_amdgcn_rcpf(1.f + __expf(-pr));
        float zg = __builtin_amdgcn_rcpf(1.f + __expf(-pz));
        float na = giN[t2] + rg * acc[4 + t2][0];
        float e2 = __expf(2.f * na);
        float ng = 1.f - 2.f * __builtin_amdgcn_rcpf(e2 + 1.f);   // tanh
        float hn = ng + zg * (hprev[t2] - ng);                    // (1-z)*n + z*h
        hprev[t2] = hn;
        unsigned short hbits = f2b(hn);
        outp[obase + (size_t)sidx * D_ + t2 * 16] = hbits;
        hnxt[(d >> 5) * 512 + ((4 * q) + 16 * ((d >> 3) & 3)) * 8 + (d & 7)] = hbits;
      }
      asm volatile("s_waitcnt lgkmcnt(0)" ::: "memory");
      __builtin_amdgcn_s_barrier();
      asm volatile("" ::: "memory");
    };

    const unsigned int* gp = slot0 + (size_t)(cc & 1) * SLOTDW_ + (w * 64 + lane);
    unsigned int cA0 = gp[0], cA1 = gp[512], cA2 = gp[1024];
    const int sg0 = cc * 64;
    for (int s2 = 0; s2 < 64; s2 += 2){
      const unsigned int* gq = gp + (size_t)(s2 + 1) * 1536;
      unsigned int cB0 = gq[0], cB1 = gq[512], cB2 = gq[1024];
      step(hb0, hb1, cA0, cA1, cA2, sg0 + s2);
      const unsigned int* gr = gp + (size_t)((s2 + 2 < 64) ? s2 + 2 : s2) * 1536;
      cA0 = gr[0]; cA1 = gr[512]; cA2 = gr[1024];
      step(hb1, hb0, cB0, cB1, cB2, sg0 + s2 + 1);
    }
    __syncthreads();                                     // drain outp stores
    __threadfence();                                     // release seq chunk
    if (tid == 0)
      __hip_atomic_store(&scanprog[l * 16 + bi], cc + 1, __ATOMIC_RELAXED, __HIP_MEMORY_SCOPE_AGENT);
  };

  gemm_chunk(0);
  for (int c = 0; c < NCHUNK_; ++c){
    scan_chunk(c);                       // publish early -> downstream layer proceeds
    if (c + 1 < NCHUNK_) gemm_chunk(c + 1);
  }
}

// Final logits GEMM: C[M,N] = A[M,K] * Bw[N,K]^T + bias, f32 out. 128x128 tile, BK=32.
__global__ __launch_bounds__(256) void gemm_out(const unsigned short* __restrict__ A,
                                                const unsigned short* __restrict__ Bw,
                                                const float* __restrict__ bias,
                                                float* __restrict__ C,
                                                int M, int N, int K, int ldc){
  __shared__ __align__(16) unsigned short As[128 * 32];
  __shared__ __align__(16) unsigned short Bs[128 * 32];
  const int tid = threadIdx.x, lane = tid & 63, w = tid >> 6;
  const int col = lane & 15, q = lane >> 4;
  const int m0 = blockIdx.x * 128, n0 = blockIdx.y * 128;
  const int mW = (w & 1) * 64, nW = (w >> 1) * 64;
  const size_t rowb = (size_t)K * 2;

  f32x4 acc[4][4] = {};
  for (int k0 = 0; k0 < K; k0 += 32){
    __syncthreads();
    #pragma unroll
    for (int inst = 0; inst < 2; ++inst){
      int c = inst * 256 + w * 64 + lane;
      int row = c >> 2, c16 = c & 3;
      lds_load16((char*)As + (inst * 4096 + w * 1024),
                 (const char*)A  + (size_t)(m0 + row) * rowb + (size_t)k0 * 2 + c16 * 16);
      lds_load16((char*)Bs + (inst * 4096 + w * 1024),
                 (const char*)Bw + (size_t)(n0 + row) * rowb + (size_t)k0 * 2 + c16 * 16);
    }
    __syncthreads();
    s16x8 aF[4], bF[4];
    #pragma unroll
    for (int t = 0; t < 4; ++t){
      aF[t] = *(const s16x8*)&As[(mW + t * 16 + col) * 32 + q * 8];
      bF[t] = *(const s16x8*)&Bs[(nW + t * 16 + col) * 32 + q * 8];
    }
    #pragma unroll
    for (int mi = 0; mi < 4; ++mi)
      #pragma unroll
      for (int ni = 0; ni < 4; ++ni)
        acc[mi][ni] = __builtin_amdgcn_mfma_f32_16x16x32_bf16(aF[mi], bF[ni], acc[mi][ni], 0, 0, 0);
  }
  float bn[4];
  #pragma unroll
  for (int ni = 0; ni < 4; ++ni) bn[ni] = bias[n0 + nW + ni * 16 + col];
  #pragma unroll
  for (int mi = 0; mi < 4; ++mi)
    #pragma unroll
    for (int ni = 0; ni < 4; ++ni)
      #pragma unroll
      for (int i = 0; i < 4; ++i){
        int r  = m0 + mW + mi * 16 + 4 * q + i;
        int cN = n0 + nW + ni * 16 + col;
        C[(size_t)r * ldc + cN] = acc[mi][ni][i] + bn[ni];
      }
}

extern "C" void kernel_launch(void* const* d_in, const int* in_sizes, int n_in,
                              void* d_out, int out_size, void* d_ws, size_t ws_size,
                              hipStream_t stream){
  const int*   x    = (const int*)  d_in[0];
  const float* emb  = (const float*)d_in[1];
  const float* Wih  = (const float*)d_in[2];
  const float* Whh  = (const float*)d_in[3];
  const float* bih  = (const float*)d_in[4];
  const float* bhh  = (const float*)d_in[5];
  const float* Wout = (const float*)d_in[6];
  const float* bout = (const float*)d_in[7];
  float* out = (float*)d_out;

  char* ws = (char*)d_ws;
  unsigned short* bufA  = (unsigned short*)(ws);                 // 67,108,864 B (seq_e/seq1/seq3)
  unsigned short* bufB  = (unsigned short*)(ws +  67108864);     // 67,108,864 B (seq0/seq2)
  unsigned int*   giAll = (unsigned int*)  (ws + 134217728);     // 50,331,648 B (64 blk x 2 slots)
  unsigned short* wihB  = (unsigned short*)(ws + 184549376);     //  1,572,864 B
  unsigned short* whhB  = (unsigned short*)(ws + 186122240);     //  1,572,864 B
  unsigned short* woutB = (unsigned short*)(ws + 187695104);     //    131,072 B
  int*            flags = (int*)           (ws + 187826176);     //        256 B

  cast_bf16_kernel<<<3072, 256, 0, stream>>>(Wih,  wihB,  L_ * 768 * 256);
  cast_bf16_kernel<<<3072, 256, 0, stream>>>(Whh,  whhB,  L_ * 768 * 256);
  cast_bf16_kernel<<< 256, 256, 0, stream>>>(Wout, woutB, V_ * D_);
  embed_kernel<<<B_ * S_, 256, 0, stream>>>(x, emb, bufA);
  init_flags_kernel<<<1, 256, 0, stream>>>(flags);

  gru_pipe<<<64, 512, 0, stream>>>(bufA, bufB, giAll, wihB, whhB, bih, bhh, flags);

  gemm_out<<<dim3(B_ * S_ / 128, 2), 256, 0, stream>>>(bufA, woutB, bout, out,
                                                       B_ * S_, 256, 256, 256);
}

// Round 6
// 16391.948 us; speedup vs baseline: 1.6369x; 1.2014x over previous
//
#include <hip/hip_runtime.h>
#include <hip/hip_bf16.h>

// GRU backbone: B=64 S=2048 D=256 V=256 L=4
// NEW this round: paired producer/consumer blocks. 128 blocks x 512 thr:
//   blocks 0..63   : scan (l=blk>>4, bi=blk&15) — round-3 scan VERBATIM (Wh in registers
//                    loaded ONCE; no per-chunk weight traffic), plus per-chunk gates.
//   blocks 64..127 : worker (same l,bi) — gi GEMM chunks into a private 2-slot ring for
//                    its paired scan block only.
// All flags single-writer point-to-point (no wide fan-in; round-4's straggler bug gone;
// round-5's per-chunk weight-restream gone — that was the 19.7ms mechanism, FETCH 2.85GB).
// Wait graph strictly decreasing in (layer,chunk) -> acyclic; 128 blocks co-resident.
// Buffer overlay (chunk-aligned, ordered by flag chain):
//   bufA: embed seq_e -> seq1 -> seq3 (read by final GEMM); bufB: seq0 -> seq2.

#define B_ 64
#define S_ 2048
#define D_ 256
#define V_ 256
#define L_ 4
#define NCHUNK_ 32
#define SLOTDW_ 98304   // dwords per gi slot: 64 steps * 1536

typedef short  s16x8 __attribute__((ext_vector_type(8)));
typedef float  f32x4 __attribute__((ext_vector_type(4)));

static __device__ __forceinline__ unsigned short f2b(float f){
  union { float f; unsigned int u; } v; v.f = f;
  unsigned int u = v.u;
  return (unsigned short)((u + 0x7FFFu + ((u >> 16) & 1u)) >> 16);  // RNE
}
static __device__ __forceinline__ float b2f_lo(unsigned int u){
  union { unsigned int u; float f; } v; v.u = u << 16; return v.f;
}
static __device__ __forceinline__ float b2f_hi(unsigned int u){
  union { unsigned int u; float f; } v; v.u = u & 0xffff0000u; return v.f;
}

static __device__ __forceinline__ void lds_load16(void* lds, const void* g){
  __builtin_amdgcn_global_load_lds(
      (const __attribute__((address_space(1))) unsigned int*)g,
      (__attribute__((address_space(3))) unsigned int*)lds, 16, 0, 0);
}

static __device__ __forceinline__ int aload(const int* p){
  return __hip_atomic_load(p, __ATOMIC_RELAXED, __HIP_MEMORY_SCOPE_AGENT);
}
static __device__ __forceinline__ void spin_ge(const int* p, int tgt){
  int n = 0;
  while (aload(p) < tgt && n < 2000000){ __builtin_amdgcn_s_sleep(16); ++n; }
}

__global__ void cast_bf16_kernel(const float* __restrict__ src,
                                 unsigned short* __restrict__ dst, int n){
  int i = blockIdx.x * 256 + threadIdx.x;
  if (i < n) dst[i] = f2b(src[i]);
}

__global__ void embed_kernel(const int* __restrict__ x, const float* __restrict__ emb,
                             unsigned short* __restrict__ seq){
  int bs = blockIdx.x;
  int d  = threadIdx.x;
  int tok = x[bs];
  seq[(size_t)bs * D_ + d] = f2b(emb[tok * D_ + d]);
}

__global__ void init_flags_kernel(int* flags){
  int i = threadIdx.x;
  if (i < 128) flags[i] = 0;
}

// Persistent paired kernel: see header.
__global__ __launch_bounds__(512, 2) void gru_pipe(
    unsigned short* bufA, unsigned short* bufB,
    unsigned int* gi_all,
    const unsigned short* wih, const unsigned short* whh,
    const float* bih, const float* bhh,
    int* flags)
{
  __shared__ __align__(16) unsigned short smem[16384];  // 32 KB: scan h dbuf | worker As,Bs
  const int blk = blockIdx.x;
  const int tid = threadIdx.x, lane = tid & 63, w = tid >> 6;
  const int col = lane & 15, q = lane >> 4;
  int* scanprog = flags;        // [64] chunks published per scan block (single-writer)
  int* jobdone  = flags + 64;   // [64] chunks published per worker block (single-writer)

  if (blk < 64){
    // ---------------- scan role: round-3 loop verbatim + per-chunk gates ----------------
    const int l = blk >> 4, bi = blk & 15;
    const unsigned short* Wh = whh + (size_t)l * 768 * 256;
    const float* bh = bhh + l * 768;
    unsigned short* outp = (l & 1) ? bufA : bufB;
    const unsigned int* slot0 = gi_all + (size_t)blk * (2 * SLOTDW_);
    const int dbase = w * 32;   // wave owns d in [dbase, dbase+32)

    // Wh fragments in registers, loaded ONCE: bw[g*2+t2][kk], B-layout (n=lane&15, k=q*8+j)
    s16x8 bw[6][8];
    float bhv[6];
    #pragma unroll
    for (int g = 0; g < 3; ++g)
      #pragma unroll
      for (int t2 = 0; t2 < 2; ++t2){
        int gcol = g * 256 + dbase + t2 * 16 + col;
        bhv[g * 2 + t2] = bh[gcol];
        #pragma unroll
        for (int kk = 0; kk < 8; ++kk)
          bw[g * 2 + t2][kk] = *(const s16x8*)(Wh + gcol * 256 + kk * 32 + q * 8);
      }

    unsigned short* hb0 = smem;          // h dbuf in A-frag order
    unsigned short* hb1 = smem + 4096;
    for (int i = tid; i < 8192; i += 512) smem[i] = 0;   // rows 4q+1..3 stay 0 forever

    float hprev[2] = {0.f, 0.f};
    const size_t obase = (size_t)(bi * 4 + q) * (S_ * D_) + dbase + col;
    __syncthreads();

    auto step = [&](const unsigned short* hcur, unsigned short* hnxt,
                    unsigned int c0, unsigned int c1, unsigned int c2, int sidx){
      f32x4 acc[6];
      #pragma unroll
      for (int t = 0; t < 6; ++t){ f32x4 vv = {bhv[t], bhv[t], bhv[t], bhv[t]}; acc[t] = vv; }
      s16x8 a0 = *(const s16x8*)&hcur[lane * 8];
      #pragma unroll
      for (int kk = 0; kk < 8; ++kk){
        s16x8 aN = a0;
        if (kk < 7) aN = *(const s16x8*)&hcur[(kk + 1) * 512 + lane * 8];
        #pragma unroll
        for (int t = 0; t < 6; ++t)
          acc[t] = __builtin_amdgcn_mfma_f32_16x16x32_bf16(a0, bw[t][kk], acc[t], 0, 0, 0);
        a0 = aN;
      }
      float giR[2] = { b2f_lo(c0), b2f_hi(c1) };
      float giZ[2] = { b2f_hi(c0), b2f_lo(c2) };
      float giN[2] = { b2f_lo(c1), b2f_hi(c2) };
      #pragma unroll
      for (int t2 = 0; t2 < 2; ++t2){
        const int d = dbase + t2 * 16 + col;
        float pr = acc[t2][0]     + giR[t2];
        float pz = acc[2 + t2][0] + giZ[t2];
        float rg = __builtin_amdgcn_rcpf(1.f + __expf(-pr));
        float zg = __builtin_amdgcn_rcpf(1.f + __expf(-pz));
        float na = giN[t2] + rg * acc[4 + t2][0];
        float e2 = __expf(2.f * na);
        float ng = 1.f - 2.f * __builtin_amdgcn_rcpf(e2 + 1.f);   // tanh
        float hn = ng + zg * (hprev[t2] - ng);                    // (1-z)*n + z*h
        hprev[t2] = hn;
        unsigned short hbits = f2b(hn);
        outp[obase + (size_t)sidx * D_ + t2 * 16] = hbits;
        hnxt[(d >> 5) * 512 + ((4 * q) + 16 * ((d >> 3) & 3)) * 8 + (d & 7)] = hbits;
      }
      asm volatile("s_waitcnt lgkmcnt(0)" ::: "memory");
      __builtin_amdgcn_s_barrier();
      asm volatile("" ::: "memory");
    };

    for (int c = 0; c < NCHUNK_; ++c){
      if (tid == 0) spin_ge(&jobdone[blk], c + 1);       // paired worker published chunk c
      __syncthreads();
      __threadfence();                                   // acquire (inv stale gi slot lines)
      const unsigned int* gp = slot0 + (size_t)(c & 1) * SLOTDW_ + (w * 64 + lane);
      unsigned int cA0 = gp[0], cA1 = gp[512], cA2 = gp[1024];
      const int sg0 = c * 64;
      for (int s2 = 0; s2 < 64; s2 += 2){
        const unsigned int* gq = gp + (size_t)(s2 + 1) * 1536;
        unsigned int cB0 = gq[0], cB1 = gq[512], cB2 = gq[1024];
        step(hb0, hb1, cA0, cA1, cA2, sg0 + s2);
        const unsigned int* gr = gp + (size_t)((s2 + 2 < 64) ? s2 + 2 : s2) * 1536;
        cA0 = gr[0]; cA1 = gr[512]; cA2 = gr[1024];
        step(hb1, hb0, cB0, cB1, cB2, sg0 + s2 + 1);
      }
      __syncthreads();                                   // all waves' outp stores drained
      __threadfence();                                   // release seq chunk
      if (tid == 0)
        __hip_atomic_store(&scanprog[blk], c + 1, __ATOMIC_RELAXED, __HIP_MEMORY_SCOPE_AGENT);
    }
  } else {
    // ---------------- worker role: gi GEMM chunks for the paired scan block ----------------
    const int W = blk - 64;               // pair id = l*16+bi
    const int l = W >> 4, bi = W & 15;
    const unsigned short* Wi = wih + (size_t)l * 768 * 256;
    const float* bip = bih + l * 768;
    const unsigned short* inp = (l & 1) ? bufB : bufA;
    unsigned short* As = smem + 8192;
    unsigned short* Bs = smem + 12288;
    const int rr = tid >> 2, c16 = tid & 3;
    const int mW = (w & 1) * 64, nW = (w >> 1) * 32;

    for (int c = 0; c < NCHUNK_; ++c){
      if (tid == 0){
        if (c >= 2) spin_ge(&scanprog[W], c - 1);             // ring slot c&1 free
        if (l > 0)  spin_ge(&scanprog[W - 16], c + 1);        // upstream seq chunk c ready
      }
      __syncthreads();
      __threadfence();                                        // acquire (inv stale seq lines)

      unsigned short* slot = (unsigned short*)(gi_all + (size_t)W * (2 * SLOTDW_)
                                               + (size_t)(c & 1) * SLOTDW_);
      #pragma unroll 1
      for (int mt = 0; mt < 2; ++mt){
        const unsigned short* Arow = inp
            + ((size_t)(bi * 4 + 2 * mt + (rr >> 6)) * S_ + (size_t)c * 64 + (rr & 63)) * 256;
        const int bq = 2 * mt + (mW >> 6);   // batch-in-block this wave's m-half computes
        #pragma unroll 1
        for (int jn = 0; jn < 6; ++jn){
          const unsigned short* Brow = Wi + (size_t)(jn * 128 + rr) * 256;
          f32x4 acc[4][2] = {};
          for (int k0 = 0; k0 < 256; k0 += 32){
            __syncthreads();
            lds_load16((char*)As + tid * 16, (const char*)Arow + k0 * 2 + c16 * 16);
            lds_load16((char*)Bs + tid * 16, (const char*)Brow + k0 * 2 + c16 * 16);
            __syncthreads();
            s16x8 aF[4], bF[2];
            #pragma unroll
            for (int t = 0; t < 4; ++t) aF[t] = *(const s16x8*)&As[(mW + t * 16 + col) * 32 + q * 8];
            #pragma unroll
            for (int t = 0; t < 2; ++t) bF[t] = *(const s16x8*)&Bs[(nW + t * 16 + col) * 32 + q * 8];
            #pragma unroll
            for (int mi = 0; mi < 4; ++mi)
              #pragma unroll
              for (int ni = 0; ni < 2; ++ni)
                acc[mi][ni] = __builtin_amdgcn_mfma_f32_16x16x32_bf16(aF[mi], bF[ni], acc[mi][ni], 0, 0, 0);
          }
          float bn[2];
          #pragma unroll
          for (int ni = 0; ni < 2; ++ni) bn[ni] = bip[jn * 128 + nW + ni * 16 + col];
          #pragma unroll
          for (int mi = 0; mi < 4; ++mi)
            #pragma unroll
            for (int ni = 0; ni < 2; ++ni)
              #pragma unroll
              for (int i = 0; i < 4; ++i){
                int sL = mi * 16 + 4 * q + i;               // step within chunk
                int cN = jn * 128 + nW + ni * 16 + col;     // gate column 0..767
                int g = cN >> 8, d = cN & 255;
                int lane_s = (d >> 5) * 64 + bq * 16 + (d & 15);
                int j = ((d >> 4) & 1) * 3 + g;
                slot[((size_t)(sL * 3 + (j >> 1)) * 512 + lane_s) * 2 + (j & 1)]
                    = f2b(acc[mi][ni][i] + bn[ni]);
              }
        }
      }
      __syncthreads();                                      // all waves' gi stores drained
      __threadfence();                                      // release gi chunk
      if (tid == 0)
        __hip_atomic_store(&jobdone[W], c + 1, __ATOMIC_RELAXED, __HIP_MEMORY_SCOPE_AGENT);
    }
  }
}

// Final logits GEMM: C[M,N] = A[M,K] * Bw[N,K]^T + bias, f32 out. 128x128 tile, BK=32.
__global__ __launch_bounds__(256) void gemm_out(const unsigned short* __restrict__ A,
                                                const unsigned short* __restrict__ Bw,
                                                const float* __restrict__ bias,
                                                float* __restrict__ C,
                                                int M, int N, int K, int ldc){
  __shared__ __align__(16) unsigned short As[128 * 32];
  __shared__ __align__(16) unsigned short Bs[128 * 32];
  const int tid = threadIdx.x, lane = tid & 63, w = tid >> 6;
  const int col = lane & 15, q = lane >> 4;
  const int m0 = blockIdx.x * 128, n0 = blockIdx.y * 128;
  const int mW = (w & 1) * 64, nW = (w >> 1) * 64;
  const size_t rowb = (size_t)K * 2;

  f32x4 acc[4][4] = {};
  for (int k0 = 0; k0 < K; k0 += 32){
    __syncthreads();
    #pragma unroll
    for (int inst = 0; inst < 2; ++inst){
      int c = inst * 256 + w * 64 + lane;
      int row = c >> 2, c16 = c & 3;
      lds_load16((char*)As + (inst * 4096 + w * 1024),
                 (const char*)A  + (size_t)(m0 + row) * rowb + (size_t)k0 * 2 + c16 * 16);
      lds_load16((char*)Bs + (inst * 4096 + w * 1024),
                 (const char*)Bw + (size_t)(n0 + row) * rowb + (size_t)k0 * 2 + c16 * 16);
    }
    __syncthreads();
    s16x8 aF[4], bF[4];
    #pragma unroll
    for (int t = 0; t < 4; ++t){
      aF[t] = *(const s16x8*)&As[(mW + t * 16 + col) * 32 + q * 8];
      bF[t] = *(const s16x8*)&Bs[(nW + t * 16 + col) * 32 + q * 8];
    }
    #pragma unroll
    for (int mi = 0; mi < 4; ++mi)
      #pragma unroll
      for (int ni = 0; ni < 4; ++ni)
        acc[mi][ni] = __builtin_amdgcn_mfma_f32_16x16x32_bf16(aF[mi], bF[ni], acc[mi][ni], 0, 0, 0);
  }
  float bn[4];
  #pragma unroll
  for (int ni = 0; ni < 4; ++ni) bn[ni] = bias[n0 + nW + ni * 16 + col];
  #pragma unroll
  for (int mi = 0; mi < 4; ++mi)
    #pragma unroll
    for (int ni = 0; ni < 4; ++ni)
      #pragma unroll
      for (int i = 0; i < 4; ++i){
        int r  = m0 + mW + mi * 16 + 4 * q + i;
        int cN = n0 + nW + ni * 16 + col;
        C[(size_t)r * ldc + cN] = acc[mi][ni][i] + bn[ni];
      }
}

extern "C" void kernel_launch(void* const* d_in, const int* in_sizes, int n_in,
                              void* d_out, int out_size, void* d_ws, size_t ws_size,
                              hipStream_t stream){
  const int*   x    = (const int*)  d_in[0];
  const float* emb  = (const float*)d_in[1];
  const float* Wih  = (const float*)d_in[2];
  const float* Whh  = (const float*)d_in[3];
  const float* bih  = (const float*)d_in[4];
  const float* bhh  = (const float*)d_in[5];
  const float* Wout = (const float*)d_in[6];
  const float* bout = (const float*)d_in[7];
  float* out = (float*)d_out;

  char* ws = (char*)d_ws;
  unsigned short* bufA  = (unsigned short*)(ws);                 // 67,108,864 B (seq_e/seq1/seq3)
  unsigned short* bufB  = (unsigned short*)(ws +  67108864);     // 67,108,864 B (seq0/seq2)
  unsigned int*   giAll = (unsigned int*)  (ws + 134217728);     // 50,331,648 B (64 pairs x 2 slots)
  unsigned short* wihB  = (unsigned short*)(ws + 184549376);     //  1,572,864 B
  unsigned short* whhB  = (unsigned short*)(ws + 186122240);     //  1,572,864 B
  unsigned short* woutB = (unsigned short*)(ws + 187695104);     //    131,072 B
  int*            flags = (int*)           (ws + 187826176);     //        512 B

  cast_bf16_kernel<<<3072, 256, 0, stream>>>(Wih,  wihB,  L_ * 768 * 256);
  cast_bf16_kernel<<<3072, 256, 0, stream>>>(Whh,  whhB,  L_ * 768 * 256);
  cast_bf16_kernel<<< 256, 256, 0, stream>>>(Wout, woutB, V_ * D_);
  embed_kernel<<<B_ * S_, 256, 0, stream>>>(x, emb, bufA);
  init_flags_kernel<<<1, 256, 0, stream>>>(flags);

  gru_pipe<<<128, 512, 0, stream>>>(bufA, bufB, giAll, wihB, whhB, bih, bhh, flags);

  gemm_out<<<dim3(B_ * S_ / 128, 2), 256, 0, stream>>>(bufA, woutB, bout, out,
                                                       B_ * S_, 256, 256, 256);
}